// Round 1
// baseline (5553.531 us; speedup 1.0000x reference)
//
#include <hip/hip_runtime.h>
#include <math.h>

#define N_PTS 131072
#define HID 256

// Fused PINN MLP forward + forward-mode Taylor streams.
// S = 1: value only (bound)             -> out[3N + i]
// S = 2: value + d/dt (init)            -> out[N + i], out[2N + i]
// S = 4: value, d_{(1,1)}, d_{(1,-1)}, mixed 2nd (equation)
//        mixed 2nd along (1,1),(1,-1) == u_tt - u_xx  -> out[0 + i]
template<int S>
__global__ void pinn_fused(const float* __restrict__ W0, const float* __restrict__ b0,
                           const float* __restrict__ W1, const float* __restrict__ b1,
                           const float* __restrict__ W2, const float* __restrict__ b2,
                           const float* __restrict__ W3, const float* __restrict__ b3,
                           const float* __restrict__ W4, const float* __restrict__ b4,
                           const float* __restrict__ tx, float* __restrict__ out)
{
    constexpr int P  = 16;  // points per block
    constexpr int J  = 8;   // neurons per thread
    constexpr int PS = 2;   // points per thread (8 point-groups)
    __shared__ float act[S][P][HID];

    const int tid = threadIdx.x;
    const int jg  = tid & 31;   // 32 neuron groups of 8
    const int pg  = tid >> 5;   // 8 point groups of 2
    const int j0  = jg * J;
    const int pbase = blockIdx.x * P;

    // ---------------- layer 0: 2 -> 256 ----------------
    #pragma unroll
    for (int p = 0; p < PS; ++p) {
        const int pp = pg * PS + p;
        const float t = tx[2 * (pbase + pp) + 0];
        const float x = tx[2 * (pbase + pp) + 1];
        #pragma unroll
        for (int jj = 0; jj < J; ++jj) {
            const int j  = j0 + jj;
            const float w0 = W0[j];          // row for input t
            const float w1 = W0[HID + j];    // row for input x
            const float z  = fmaf(t, w0, fmaf(x, w1, b0[j]));
            const float h  = tanhf(z);
            act[0][pp][j] = h;
            if (S >= 2) {
                const float f1 = 1.0f - h * h;
                if (S == 2) {
                    act[1][pp][j] = f1 * w0;            // d z / d t
                } else {
                    const float d1 = w0 + w1;           // dir (1,1)
                    const float d2 = w0 - w1;           // dir (1,-1)
                    const float f2 = -2.0f * h * f1;
                    act[1][pp][j] = f1 * d1;
                    act[2][pp][j] = f1 * d2;
                    act[3][pp][j] = f2 * d1 * d2;       // z-mixed is 0
                }
            }
        }
    }
    __syncthreads();

    // ---------------- layers 1..3: 256 -> 256 + tanh ----------------
    auto do_layer = [&](const float* __restrict__ W, const float* __restrict__ bl) {
        float acc[S][PS][J];
        #pragma unroll
        for (int s = 0; s < S; ++s)
            #pragma unroll
            for (int p = 0; p < PS; ++p)
                #pragma unroll
                for (int jj = 0; jj < J; ++jj)
                    acc[s][p][jj] = 0.0f;

        for (int k = 0; k < HID; k += 4) {
            float wreg[4][J];
            #pragma unroll
            for (int kk = 0; kk < 4; ++kk) {
                const float* wr = W + (size_t)(k + kk) * HID + j0;
                const float4 a = *reinterpret_cast<const float4*>(wr);
                const float4 b = *reinterpret_cast<const float4*>(wr + 4);
                wreg[kk][0] = a.x; wreg[kk][1] = a.y; wreg[kk][2] = a.z; wreg[kk][3] = a.w;
                wreg[kk][4] = b.x; wreg[kk][5] = b.y; wreg[kk][6] = b.z; wreg[kk][7] = b.w;
            }
            #pragma unroll
            for (int s = 0; s < S; ++s) {
                #pragma unroll
                for (int p = 0; p < PS; ++p) {
                    const float4 inv = *reinterpret_cast<const float4*>(&act[s][pg * PS + p][k]);
                    const float iv[4] = {inv.x, inv.y, inv.z, inv.w};
                    #pragma unroll
                    for (int kk = 0; kk < 4; ++kk)
                        #pragma unroll
                        for (int jj = 0; jj < J; ++jj)
                            acc[s][p][jj] = fmaf(iv[kk], wreg[kk][jj], acc[s][p][jj]);
                }
            }
        }
        __syncthreads();   // all reads of act done before overwrite

        float bj[J];
        #pragma unroll
        for (int jj = 0; jj < J; ++jj) bj[jj] = bl[j0 + jj];

        #pragma unroll
        for (int p = 0; p < PS; ++p) {
            const int pp = pg * PS + p;
            #pragma unroll
            for (int jj = 0; jj < J; ++jj) {
                const int j = j0 + jj;
                const float z = acc[0][p][jj] + bj[jj];
                const float h = tanhf(z);
                act[0][pp][j] = h;
                if (S >= 2) {
                    const float f1 = 1.0f - h * h;
                    if (S == 2) {
                        act[1][pp][j] = f1 * acc[1][p][jj];
                    } else {
                        const float z1 = acc[1][p][jj];
                        const float z2 = acc[2][p][jj];
                        const float zm = acc[3][p][jj];
                        const float f2 = -2.0f * h * f1;
                        act[1][pp][j] = f1 * z1;
                        act[2][pp][j] = f1 * z2;
                        act[3][pp][j] = fmaf(f1, zm, f2 * z1 * z2);
                    }
                }
            }
        }
        __syncthreads();
    };

    do_layer(W1, b1);
    do_layer(W2, b2);
    do_layer(W3, b3);

    // ---------------- layer 4: 256 -> 1 ----------------
    {
        const int p   = tid >> 4;    // 0..15 : point
        const int seg = tid & 15;    // 16 lanes per point
        const int k0  = seg * 16;
        const int pt  = pbase + p;

        if (S == 4) {
            float pm = 0.0f;
            #pragma unroll
            for (int k = 0; k < 16; ++k) pm = fmaf(act[3][p][k0 + k], W4[k0 + k], pm);
            #pragma unroll
            for (int off = 8; off > 0; off >>= 1) pm += __shfl_down(pm, off, 16);
            if (seg == 0) out[0 * N_PTS + pt] = pm;             // u_tt - u_xx
        } else if (S == 2) {
            float pu = 0.0f, pd = 0.0f;
            #pragma unroll
            for (int k = 0; k < 16; ++k) {
                const float wv = W4[k0 + k];
                pu = fmaf(act[0][p][k0 + k], wv, pu);
                pd = fmaf(act[1][p][k0 + k], wv, pd);
            }
            #pragma unroll
            for (int off = 8; off > 0; off >>= 1) {
                pu += __shfl_down(pu, off, 16);
                pd += __shfl_down(pd, off, 16);
            }
            if (seg == 0) {
                out[1 * N_PTS + pt] = pu + b4[0];               // u_phi
                out[2 * N_PTS + pt] = pd;                       // du/dt
            }
        } else {
            float pu = 0.0f;
            #pragma unroll
            for (int k = 0; k < 16; ++k) pu = fmaf(act[0][p][k0 + k], W4[k0 + k], pu);
            #pragma unroll
            for (int off = 8; off > 0; off >>= 1) pu += __shfl_down(pu, off, 16);
            if (seg == 0) out[3 * N_PTS + pt] = pu + b4[0];     // u_bound
        }
    }
}

extern "C" void kernel_launch(void* const* d_in, const int* in_sizes, int n_in,
                              void* d_out, int out_size, void* d_ws, size_t ws_size,
                              hipStream_t stream) {
    const float* W0 = (const float*)d_in[0];
    const float* b0 = (const float*)d_in[1];
    const float* W1 = (const float*)d_in[2];
    const float* b1 = (const float*)d_in[3];
    const float* W2 = (const float*)d_in[4];
    const float* b2 = (const float*)d_in[5];
    const float* W3 = (const float*)d_in[6];
    const float* b3 = (const float*)d_in[7];
    const float* W4 = (const float*)d_in[8];
    const float* b4 = (const float*)d_in[9];
    const float* tx_eq    = (const float*)d_in[10];
    const float* tx_init  = (const float*)d_in[11];
    const float* tx_bound = (const float*)d_in[12];
    float* out = (float*)d_out;

    dim3 block(256);
    dim3 grid(N_PTS / 16);

    pinn_fused<4><<<grid, block, 0, stream>>>(W0, b0, W1, b1, W2, b2, W3, b3, W4, b4, tx_eq, out);
    pinn_fused<2><<<grid, block, 0, stream>>>(W0, b0, W1, b1, W2, b2, W3, b3, W4, b4, tx_init, out);
    pinn_fused<1><<<grid, block, 0, stream>>>(W0, b0, W1, b1, W2, b2, W3, b3, W4, b4, tx_bound, out);
}

// Round 2
// 1402.525 us; speedup vs baseline: 3.9597x; 3.9597x over previous
//
#include <hip/hip_runtime.h>
#include <math.h>

#define N_PTS 131072
#define HID   256

typedef __attribute__((ext_vector_type(8))) _Float16 f16x8;
typedef __attribute__((ext_vector_type(4))) float    f32x4;
typedef unsigned int u32;
typedef __attribute__((address_space(1))) const u32 gu32;
typedef __attribute__((address_space(3))) u32       lu32;

// LDS map (dynamic, 128 KiB): act_hi[64][256] f16 | act_lo | W double-buffer (z overlay)
#define LDS_HI  0
#define LDS_LO  32768
#define LDS_W   65536
#define LDS_SZ  131072
#define LO_SCALE 4096.0f
#define LO_INV   (1.0f/4096.0f)

// act plane: [row][k] f16, XOR swizzle -> b128 A-frag reads are conflict-optimal
__device__ __forceinline__ int act_off(int row, int kbyte) {
    return row * 512 + (kbyte ^ ((row & 7) << 4));
}
// z overlay: [row][col] f32, XOR on (row>>2) spreads the 4-row acc dump
__device__ __forceinline__ int z_off(int row, int cbyte) {
    return row * 1024 + (cbyte ^ (((row >> 2) & 3) << 5));
}
// W slab in LDS: [n][32k] f16 (transposed), slot XOR on (n>>1) -> conflict-optimal B-frags
__device__ __forceinline__ int w_off(int n, int kg) {
    return n * 64 + ((kg ^ ((n >> 1) & 3)) << 4);
}
__device__ __forceinline__ float fast_tanh(float z) {
    float zc = fminf(fmaxf(z, -15.0f), 15.0f);
    float t  = __expf(2.0f * zc);
    return __fdividef(t - 1.0f, t + 1.0f);   // abs err ~1e-7, saturates correctly
}
__device__ __forceinline__ void split_hl(float v, _Float16 &hi, _Float16 &lo) {
    hi = (_Float16)v;
    lo = (_Float16)((v - (float)hi) * LO_SCALE);  // scaled: avoids f16 denorm flush
}

// Pre-split W1..W3 into f16 hi/lo, transposed to [n][k] with the LDS swizzle
// pre-applied (m173 pattern: swizzle in global, global_load_lds stays linear).
// d_ws layout: [layer 0..2][slab 0..7] x 32KB block = [hi 16KB][lo 16KB]. 768KB total.
__global__ void prep_w(const float* __restrict__ W1, const float* __restrict__ W2,
                       const float* __restrict__ W3, char* __restrict__ ws)
{
    int idx = blockIdx.x * 256 + threadIdx.x;      // 3*65536 elements
    int l = idx >> 16;
    int e = idx & 65535;
    int k = e >> 8, n = e & 255;
    const float* W = (l == 0) ? W1 : (l == 1) ? W2 : W3;
    float w = W[e];
    _Float16 hi, lo;
    split_hl(w, hi, lo);
    int kk = k & 31;
    int byte_in = w_off(n, kk >> 3) + (kk & 7) * 2;
    char* base = ws + (size_t)(l * 8 + (k >> 5)) * 32768;
    *(_Float16*)(base + byte_in)         = hi;
    *(_Float16*)(base + 16384 + byte_in) = lo;
}

// Fused PINN forward + Taylor streams, f16 split-precision MFMA.
// S=4 (equation: v, d_{(1,1)}, d_{(1,-1)}, mixed), S=2 (init: v, d/dt), S=1 (bound).
// rows = S*PTS = 64 GEMM rows per block; 8 waves, wave w owns cols [32w,32w+32).
template<int S, int PTS>
__global__ void __launch_bounds__(512, 1)
pinn_mfma(const float* __restrict__ W0, const float* __restrict__ b0,
          const float* __restrict__ b1, const float* __restrict__ b2,
          const float* __restrict__ b3,
          const float* __restrict__ W4, const float* __restrict__ b4,
          const char* __restrict__ wpre,
          const float* __restrict__ tx, float* __restrict__ out)
{
    extern __shared__ char lds[];
    const int tid  = threadIdx.x;
    const int lane = tid & 63;
    const int wid  = tid >> 6;
    const int pbase = blockIdx.x * PTS;
    constexpr int CG = 512 / PTS;     // threads per point
    constexpr int NC = 256 / CG;      // cols per thread (elementwise)
    const int ep  = tid / CG;
    const int ec0 = (tid % CG) * NC;

    // ---------------- layer 0: 2 -> 256 (elementwise) ----------------
    {
        const float tt = tx[2 * (pbase + ep) + 0];
        const float xx = tx[2 * (pbase + ep) + 1];
        for (int cb = ec0; cb < ec0 + NC; cb += 8) {
            alignas(16) float w0r[8], w1r[8], bb[8];
            *(f32x4*)&w0r[0] = *(const f32x4*)(W0 + cb);
            *(f32x4*)&w0r[4] = *(const f32x4*)(W0 + cb + 4);
            *(f32x4*)&w1r[0] = *(const f32x4*)(W0 + HID + cb);
            *(f32x4*)&w1r[4] = *(const f32x4*)(W0 + HID + cb + 4);
            *(f32x4*)&bb[0]  = *(const f32x4*)(b0 + cb);
            *(f32x4*)&bb[4]  = *(const f32x4*)(b0 + cb + 4);
            f16x8 vhi[S], vlo[S];
            #pragma unroll
            for (int j = 0; j < 8; ++j) {
                float z = fmaf(tt, w0r[j], fmaf(xx, w1r[j], bb[j]));
                float h = fast_tanh(z);
                float f1 = 1.0f - h * h;
                _Float16 hh, hl;
                split_hl(h, hh, hl); vhi[0][j] = hh; vlo[0][j] = hl;
                if (S == 2) {
                    split_hl(f1 * w0r[j], hh, hl); vhi[1][j] = hh; vlo[1][j] = hl;
                } else if (S == 4) {
                    float d1 = w0r[j] + w1r[j];
                    float d2 = w0r[j] - w1r[j];
                    float f2 = -2.0f * h * f1;
                    split_hl(f1 * d1, hh, hl);      vhi[1][j] = hh; vlo[1][j] = hl;
                    split_hl(f1 * d2, hh, hl);      vhi[2][j] = hh; vlo[2][j] = hl;
                    split_hl(f2 * d1 * d2, hh, hl); vhi[3][j] = hh; vlo[3][j] = hl;
                }
            }
            #pragma unroll
            for (int s2 = 0; s2 < S; ++s2) {
                int row = s2 * PTS + ep;
                *(f16x8*)(lds + LDS_HI + act_off(row, cb * 2)) = vhi[s2];
                *(f16x8*)(lds + LDS_LO + act_off(row, cb * 2)) = vlo[s2];
            }
        }
    }
    __syncthreads();

    // ---------------- layers 1..3: 256 -> 256 (split-f16 MFMA) ----------------
    const int wcb = wid * 32;
    for (int l = 0; l < 3; ++l) {
        const char* wsrc = wpre + (size_t)l * 8 * 32768;

        f32x4 am[4][2], al[4][2];     // main-scale and lo-scale accumulators
        #pragma unroll
        for (int rt = 0; rt < 4; ++rt)
            #pragma unroll
            for (int ct = 0; ct < 2; ++ct) {
                am[rt][ct] = (f32x4){0.f, 0.f, 0.f, 0.f};
                al[rt][ct] = (f32x4){0.f, 0.f, 0.f, 0.f};
            }

        // stage slab 0 (32KB: hi 16K + lo 16K, linear copy of pre-swizzled data)
        {
            const char* src = wsrc;
            char* dst = lds + LDS_W;
            #pragma unroll
            for (int q = 0; q < 4; ++q) {
                int o = (wid * 4 + q) * 1024;
                __builtin_amdgcn_global_load_lds((gu32*)(src + o + lane * 16),
                                                 (lu32*)(dst + o), 16, 0, 0);
            }
        }
        __syncthreads();

        for (int s = 0; s < 8; ++s) {
            if (s < 7) {   // prefetch next slab into other buffer
                const char* src = wsrc + (size_t)(s + 1) * 32768;
                char* dst = lds + LDS_W + ((s + 1) & 1) * 32768;
                #pragma unroll
                for (int q = 0; q < 4; ++q) {
                    int o = (wid * 4 + q) * 1024;
                    __builtin_amdgcn_global_load_lds((gu32*)(src + o + lane * 16),
                                                     (lu32*)(dst + o), 16, 0, 0);
                }
            }
            // compute slab s: A-frag k = s*32 + (lane>>4)*8 + j, row = rt*16 + (lane&15)
            {
                const int kbyte = s * 64 + ((lane >> 4) << 4);
                f16x8 ahi[4], alo[4];
                #pragma unroll
                for (int rt = 0; rt < 4; ++rt) {
                    int row = rt * 16 + (lane & 15);
                    ahi[rt] = *(const f16x8*)(lds + LDS_HI + act_off(row, kbyte));
                    alo[rt] = *(const f16x8*)(lds + LDS_LO + act_off(row, kbyte));
                }
                const char* wb = lds + LDS_W + (s & 1) * 32768;
                #pragma unroll
                for (int ct = 0; ct < 2; ++ct) {
                    const int n  = wcb + ct * 16 + (lane & 15);
                    const int wo = w_off(n, lane >> 4);
                    f16x8 bhi = *(const f16x8*)(wb + wo);
                    f16x8 blo = *(const f16x8*)(wb + 16384 + wo);
                    #pragma unroll
                    for (int rt = 0; rt < 4; ++rt) {
                        am[rt][ct] = __builtin_amdgcn_mfma_f32_16x16x32_f16(ahi[rt], bhi, am[rt][ct], 0, 0, 0);
                        al[rt][ct] = __builtin_amdgcn_mfma_f32_16x16x32_f16(ahi[rt], blo, al[rt][ct], 0, 0, 0);
                        al[rt][ct] = __builtin_amdgcn_mfma_f32_16x16x32_f16(alo[rt], bhi, al[rt][ct], 0, 0, 0);
                    }
                }
            }
            __syncthreads();
        }

        // dump z = am + al/4096 into W-buffer region (free now)
        #pragma unroll
        for (int rt = 0; rt < 4; ++rt)
            #pragma unroll
            for (int ct = 0; ct < 2; ++ct)
                #pragma unroll
                for (int r = 0; r < 4; ++r) {
                    int row = rt * 16 + (lane >> 4) * 4 + r;   // m89-verified C/D layout
                    int col = wcb + ct * 16 + (lane & 15);
                    float zv = am[rt][ct][r] + al[rt][ct][r] * LO_INV;
                    *(float*)(lds + LDS_W + z_off(row, col * 4)) = zv;
                }
        __syncthreads();

        // elementwise: bias + tanh + stream chain + hi/lo re-split
        {
            const float* bl = (l == 0) ? b1 : (l == 1) ? b2 : b3;
            for (int cb = ec0; cb < ec0 + NC; cb += 8) {
                alignas(16) float zz[S][8];
                #pragma unroll
                for (int s2 = 0; s2 < S; ++s2) {
                    int row = s2 * PTS + ep;
                    *(f32x4*)&zz[s2][0] = *(const f32x4*)(lds + LDS_W + z_off(row, cb * 4));
                    *(f32x4*)&zz[s2][4] = *(const f32x4*)(lds + LDS_W + z_off(row, cb * 4 + 16));
                }
                alignas(16) float bb[8];
                *(f32x4*)&bb[0] = *(const f32x4*)(bl + cb);
                *(f32x4*)&bb[4] = *(const f32x4*)(bl + cb + 4);
                f16x8 vhi[S], vlo[S];
                #pragma unroll
                for (int j = 0; j < 8; ++j) {
                    float h  = fast_tanh(zz[0][j] + bb[j]);
                    float f1 = 1.0f - h * h;
                    _Float16 hh, hl;
                    split_hl(h, hh, hl); vhi[0][j] = hh; vlo[0][j] = hl;
                    if (S == 2) {
                        split_hl(f1 * zz[1][j], hh, hl); vhi[1][j] = hh; vlo[1][j] = hl;
                    } else if (S == 4) {
                        float f2 = -2.0f * h * f1;
                        split_hl(f1 * zz[1][j], hh, hl); vhi[1][j] = hh; vlo[1][j] = hl;
                        split_hl(f1 * zz[2][j], hh, hl); vhi[2][j] = hh; vlo[2][j] = hl;
                        split_hl(fmaf(f1, zz[3][j], f2 * zz[1][j] * zz[2][j]), hh, hl);
                        vhi[3][j] = hh; vlo[3][j] = hl;
                    }
                }
                #pragma unroll
                for (int s2 = 0; s2 < S; ++s2) {
                    int row = s2 * PTS + ep;
                    *(f16x8*)(lds + LDS_HI + act_off(row, cb * 2)) = vhi[s2];
                    *(f16x8*)(lds + LDS_LO + act_off(row, cb * 2)) = vlo[s2];
                }
            }
        }
        __syncthreads();
    }

    // ---------------- layer 4: 256 -> 1 ----------------
    {
        const int row = tid >> 3;      // 64 rows
        const int seg = tid & 7;       // 8 lanes per row
        const int k0  = seg * 32;
        float d = 0.0f;
        #pragma unroll
        for (int kb = 0; kb < 32; kb += 8) {
            int kbyte = (k0 + kb) * 2;
            f16x8 h8 = *(const f16x8*)(lds + LDS_HI + act_off(row, kbyte));
            f16x8 l8 = *(const f16x8*)(lds + LDS_LO + act_off(row, kbyte));
            alignas(16) float wv[8];
            *(f32x4*)&wv[0] = *(const f32x4*)(W4 + k0 + kb);
            *(f32x4*)&wv[4] = *(const f32x4*)(W4 + k0 + kb + 4);
            #pragma unroll
            for (int j = 0; j < 8; ++j)
                d = fmaf((float)h8[j] + (float)l8[j] * LO_INV, wv[j], d);
        }
        d += __shfl_down(d, 4, 8);
        d += __shfl_down(d, 2, 8);
        d += __shfl_down(d, 1, 8);
        if (seg == 0) {
            if (S == 4) {
                if (row >= 3 * PTS) out[0 * N_PTS + pbase + (row - 3 * PTS)] = d;      // u_tt - u_xx
            } else if (S == 2) {
                if (row < PTS) out[1 * N_PTS + pbase + row] = d + b4[0];               // u_phi
                else           out[2 * N_PTS + pbase + (row - PTS)] = d;               // du/dt
            } else {
                out[3 * N_PTS + pbase + row] = d + b4[0];                              // u_bound
            }
        }
    }
}

extern "C" void kernel_launch(void* const* d_in, const int* in_sizes, int n_in,
                              void* d_out, int out_size, void* d_ws, size_t ws_size,
                              hipStream_t stream) {
    const float* W0 = (const float*)d_in[0];
    const float* b0 = (const float*)d_in[1];
    const float* W1 = (const float*)d_in[2];
    const float* b1 = (const float*)d_in[3];
    const float* W2 = (const float*)d_in[4];
    const float* b2 = (const float*)d_in[5];
    const float* W3 = (const float*)d_in[6];
    const float* b3 = (const float*)d_in[7];
    const float* W4 = (const float*)d_in[8];
    const float* b4 = (const float*)d_in[9];
    const float* tx_eq    = (const float*)d_in[10];
    const float* tx_init  = (const float*)d_in[11];
    const float* tx_bound = (const float*)d_in[12];
    float* out = (float*)d_out;
    char* wpre = (char*)d_ws;     // needs 768KB

    // opt-in to >64KB dynamic LDS (idempotent, not a stream op -> capture-safe)
    hipFuncSetAttribute((const void*)pinn_mfma<4,16>, hipFuncAttributeMaxDynamicSharedMemorySize, LDS_SZ);
    hipFuncSetAttribute((const void*)pinn_mfma<2,32>, hipFuncAttributeMaxDynamicSharedMemorySize, LDS_SZ);
    hipFuncSetAttribute((const void*)pinn_mfma<1,64>, hipFuncAttributeMaxDynamicSharedMemorySize, LDS_SZ);

    prep_w<<<768, 256, 0, stream>>>(W1, W2, W3, wpre);
    pinn_mfma<4,16><<<N_PTS/16, 512, LDS_SZ, stream>>>(W0,b0,b1,b2,b3,W4,b4,wpre,tx_eq,   out);
    pinn_mfma<2,32><<<N_PTS/32, 512, LDS_SZ, stream>>>(W0,b0,b1,b2,b3,W4,b4,wpre,tx_init, out);
    pinn_mfma<1,64><<<N_PTS/64, 512, LDS_SZ, stream>>>(W0,b0,b1,b2,b3,W4,b4,wpre,tx_bound,out);
}

// Round 3
// 1396.067 us; speedup vs baseline: 3.9780x; 1.0046x over previous
//
#include <hip/hip_runtime.h>
#include <math.h>

#define N_PTS 131072
#define HID   256

typedef __attribute__((ext_vector_type(8))) _Float16 f16x8;
typedef __attribute__((ext_vector_type(4))) float    f32x4;
typedef unsigned int u32;
typedef __attribute__((address_space(1))) const u32 gu32;
typedef __attribute__((address_space(3))) u32       lu32;

// LDS map (dynamic, 128 KiB): act_hi[64][256] f16 | act_lo | W double-buffer
#define LDS_HI  0
#define LDS_LO  32768
#define LDS_W   65536
#define LDS_SZ  131072
#define LO_SCALE 4096.0f
#define LO_INV   (1.0f/4096.0f)

// act plane: [row][k] f16, XOR swizzle -> b128 A-frag reads conflict-optimal
__device__ __forceinline__ int act_off(int row, int kbyte) {
    return row * 512 + (kbyte ^ ((row & 7) << 4));
}
// W slab in LDS: [n][32k] f16 (transposed), slot XOR on (n>>1) -> conflict-optimal B-frags
__device__ __forceinline__ int w_off(int n, int kg) {
    return n * 64 + ((kg ^ ((n >> 1) & 3)) << 4);
}
__device__ __forceinline__ float fast_tanh(float z) {
    float zc = fminf(fmaxf(z, -15.0f), 15.0f);
    float t  = __expf(2.0f * zc);
    return __fdividef(t - 1.0f, t + 1.0f);   // abs err ~1e-7, saturates correctly
}
__device__ __forceinline__ void split_hl(float v, _Float16 &hi, _Float16 &lo) {
    hi = (_Float16)v;
    lo = (_Float16)((v - (float)hi) * LO_SCALE);  // scaled: avoids f16 denorm flush
}

// Pre-split W1..W3 into f16 hi/lo, transposed to [n][k], LDS swizzle pre-applied.
// d_ws: [layer 0..2][slab 0..7] x 32KB = [hi 16KB][lo 16KB]. 768KB total.
__global__ void prep_w(const float* __restrict__ W1, const float* __restrict__ W2,
                       const float* __restrict__ W3, char* __restrict__ ws)
{
    int idx = blockIdx.x * 256 + threadIdx.x;      // 3*65536 elements
    int l = idx >> 16;
    int e = idx & 65535;
    int k = e >> 8, n = e & 255;
    const float* W = (l == 0) ? W1 : (l == 1) ? W2 : W3;
    float w = W[e];
    _Float16 hi, lo;
    split_hl(w, hi, lo);
    int kk = k & 31;
    int byte_in = w_off(n, kk >> 3) + (kk & 7) * 2;
    char* base = ws + (size_t)(l * 8 + (k >> 5)) * 32768;
    *(_Float16*)(base + byte_in)         = hi;
    *(_Float16*)(base + 16384 + byte_in) = lo;
}

// Fused PINN forward + Taylor streams, f16 split-precision MFMA, in-register epilogue.
template<int S, int PTS>
__global__ void __launch_bounds__(512, 1)
pinn_mfma(const float* __restrict__ W0, const float* __restrict__ b0,
          const float* __restrict__ b1, const float* __restrict__ b2,
          const float* __restrict__ b3,
          const float* __restrict__ W4, const float* __restrict__ b4,
          const char* __restrict__ wpre,
          const float* __restrict__ tx, float* __restrict__ out)
{
    extern __shared__ char lds[];
    const int tid  = threadIdx.x;
    const int lane = tid & 63;
    const int wid  = tid >> 6;
    const int pbase = blockIdx.x * PTS;
    constexpr int CG = 512 / PTS;     // threads per point (layer 0)
    constexpr int NC = 256 / CG;      // cols per thread (layer 0)
    const int ep  = tid / CG;
    const int ec0 = (tid % CG) * NC;
    const int wcb = wid * 32;         // wave's 32-col slice

    // ---------------- layer 0: 2 -> 256 (elementwise into LDS act) ----------------
    {
        const float tt = tx[2 * (pbase + ep) + 0];
        const float xx = tx[2 * (pbase + ep) + 1];
        for (int cb = ec0; cb < ec0 + NC; cb += 8) {
            alignas(16) float w0r[8], w1r[8], bb[8];
            *(f32x4*)&w0r[0] = *(const f32x4*)(W0 + cb);
            *(f32x4*)&w0r[4] = *(const f32x4*)(W0 + cb + 4);
            *(f32x4*)&w1r[0] = *(const f32x4*)(W0 + HID + cb);
            *(f32x4*)&w1r[4] = *(const f32x4*)(W0 + HID + cb + 4);
            *(f32x4*)&bb[0]  = *(const f32x4*)(b0 + cb);
            *(f32x4*)&bb[4]  = *(const f32x4*)(b0 + cb + 4);
            f16x8 vhi[S], vlo[S];
            #pragma unroll
            for (int j = 0; j < 8; ++j) {
                float z = fmaf(tt, w0r[j], fmaf(xx, w1r[j], bb[j]));
                float h = fast_tanh(z);
                float f1 = 1.0f - h * h;
                _Float16 hh, hl;
                split_hl(h, hh, hl); vhi[0][j] = hh; vlo[0][j] = hl;
                if (S == 2) {
                    split_hl(f1 * w0r[j], hh, hl); vhi[1][j] = hh; vlo[1][j] = hl;
                } else if (S == 4) {
                    float d1 = w0r[j] + w1r[j];
                    float d2 = w0r[j] - w1r[j];
                    float f2 = -2.0f * h * f1;
                    split_hl(f1 * d1, hh, hl);      vhi[1][j] = hh; vlo[1][j] = hl;
                    split_hl(f1 * d2, hh, hl);      vhi[2][j] = hh; vlo[2][j] = hl;
                    split_hl(f2 * d1 * d2, hh, hl); vhi[3][j] = hh; vlo[3][j] = hl;
                }
            }
            #pragma unroll
            for (int s2 = 0; s2 < S; ++s2) {
                int row = s2 * PTS + ep;
                *(f16x8*)(lds + LDS_HI + act_off(row, cb * 2)) = vhi[s2];
                *(f16x8*)(lds + LDS_LO + act_off(row, cb * 2)) = vlo[s2];
            }
        }
    }

    // bias preload (2 cols per lane per layer) — before any staging
    const int cA = wcb + (lane & 15);
    float bc[3][2];
    bc[0][0] = b1[cA]; bc[0][1] = b1[cA + 16];
    bc[1][0] = b2[cA]; bc[1][1] = b2[cA + 16];
    bc[2][0] = b3[cA]; bc[2][1] = b3[cA + 16];

    // stage slab 0 into buf0
    {
        const char* src = wpre;
        char* dst = lds + LDS_W;
        #pragma unroll
        for (int q = 0; q < 4; ++q) {
            int o = (wid * 4 + q) * 1024;
            __builtin_amdgcn_global_load_lds((gu32*)(src + o + lane * 16),
                                             (lu32*)(dst + o), 16, 0, 0);
        }
    }
    asm volatile("s_waitcnt lgkmcnt(0)" ::: "memory");   // act writes visible
    __builtin_amdgcn_sched_barrier(0);
    __syncthreads();                                      // also drains stage(0)

    // ---------------- layers 1..3: 256 -> 256 (split-f16 MFMA) ----------------
    #pragma unroll
    for (int l = 0; l < 3; ++l) {
        f32x4 am[4][2], al[4][2];
        #pragma unroll
        for (int rt = 0; rt < 4; ++rt)
            #pragma unroll
            for (int ct = 0; ct < 2; ++ct) {
                am[rt][ct] = (f32x4){0.f, 0.f, 0.f, 0.f};
                al[rt][ct] = (f32x4){0.f, 0.f, 0.f, 0.f};
            }

        for (int s = 0; s < 8; ++s) {
            const int g = l * 8 + s;
            if (g < 23) {   // prefetch next slab (1-deep, covered by this slab's MFMAs)
                const char* src = wpre + (size_t)(g + 1) * 32768;
                char* dst = lds + LDS_W + ((g + 1) & 1) * 32768;
                #pragma unroll
                for (int q = 0; q < 4; ++q) {
                    int o = (wid * 4 + q) * 1024;
                    __builtin_amdgcn_global_load_lds((gu32*)(src + o + lane * 16),
                                                     (lu32*)(dst + o), 16, 0, 0);
                }
            }
            // A-frags: k = s*32 + (lane>>4)*8 + j, row = rt*16 + (lane&15)
            const int kbyte = s * 64 + ((lane >> 4) << 4);
            f16x8 ahi[4], alo[4];
            #pragma unroll
            for (int rt = 0; rt < 4; ++rt) {
                int row = rt * 16 + (lane & 15);
                ahi[rt] = *(const f16x8*)(lds + LDS_HI + act_off(row, kbyte));
                alo[rt] = *(const f16x8*)(lds + LDS_LO + act_off(row, kbyte));
            }
            const char* wb = lds + LDS_W + (g & 1) * 32768;
            f16x8 bhi[2], blo[2];
            #pragma unroll
            for (int ct = 0; ct < 2; ++ct) {
                const int n  = wcb + ct * 16 + (lane & 15);
                const int wo = w_off(n, lane >> 4);
                bhi[ct] = *(const f16x8*)(wb + wo);
                blo[ct] = *(const f16x8*)(wb + 16384 + wo);
            }
            __builtin_amdgcn_s_setprio(1);
            #pragma unroll
            for (int ct = 0; ct < 2; ++ct)
                #pragma unroll
                for (int rt = 0; rt < 4; ++rt) {
                    am[rt][ct] = __builtin_amdgcn_mfma_f32_16x16x32_f16(ahi[rt], bhi[ct], am[rt][ct], 0, 0, 0);
                    al[rt][ct] = __builtin_amdgcn_mfma_f32_16x16x32_f16(ahi[rt], blo[ct], al[rt][ct], 0, 0, 0);
                    al[rt][ct] = __builtin_amdgcn_mfma_f32_16x16x32_f16(alo[rt], bhi[ct], al[rt][ct], 0, 0, 0);
                }
            __builtin_amdgcn_s_setprio(0);
            __syncthreads();   // vmcnt(0)+lgkmcnt(0)+barrier: prefetch covered by MFMAs
        }

        // ---- in-register epilogue: streams of one (point,col) live in one lane ----
        // C/D: row = rt*16 + (lane>>4)*4 + r, col = wcb + ct*16 + (lane&15)
        #pragma unroll
        for (int ct = 0; ct < 2; ++ct) {
            const int col = wcb + ct * 16 + (lane & 15);
            const float bias = bc[l][ct];
            #pragma unroll
            for (int r = 0; r < 4; ++r) {
                const int pr = (lane >> 4) * 4 + r;   // row within 16-tile
                _Float16 hh, hl;
                if (S == 4) {
                    // stream s2 == rt tile; rows s2*16 + pr
                    float z0 = am[0][ct][r] + al[0][ct][r] * LO_INV + bias;
                    float z1 = am[1][ct][r] + al[1][ct][r] * LO_INV;
                    float z2 = am[2][ct][r] + al[2][ct][r] * LO_INV;
                    float zm = am[3][ct][r] + al[3][ct][r] * LO_INV;
                    float h  = fast_tanh(z0);
                    float f1 = 1.0f - h * h;
                    float f2 = -2.0f * h * f1;
                    float v1 = f1 * z1;
                    float v2 = f1 * z2;
                    float vm = fmaf(f1, zm, f2 * z1 * z2);
                    split_hl(h, hh, hl);
                    *(_Float16*)(lds + LDS_HI + act_off(pr, col * 2)) = hh;
                    *(_Float16*)(lds + LDS_LO + act_off(pr, col * 2)) = hl;
                    split_hl(v1, hh, hl);
                    *(_Float16*)(lds + LDS_HI + act_off(16 + pr, col * 2)) = hh;
                    *(_Float16*)(lds + LDS_LO + act_off(16 + pr, col * 2)) = hl;
                    split_hl(v2, hh, hl);
                    *(_Float16*)(lds + LDS_HI + act_off(32 + pr, col * 2)) = hh;
                    *(_Float16*)(lds + LDS_LO + act_off(32 + pr, col * 2)) = hl;
                    split_hl(vm, hh, hl);
                    *(_Float16*)(lds + LDS_HI + act_off(48 + pr, col * 2)) = hh;
                    *(_Float16*)(lds + LDS_LO + act_off(48 + pr, col * 2)) = hl;
                } else if (S == 2) {
                    // value tiles rt=0,1 (rows 0-31); deriv tiles rt=2,3 (rows 32-63)
                    #pragma unroll
                    for (int v = 0; v < 2; ++v) {
                        float z0 = am[v][ct][r] + al[v][ct][r] * LO_INV + bias;
                        float zd = am[2 + v][ct][r] + al[2 + v][ct][r] * LO_INV;
                        float h  = fast_tanh(z0);
                        float f1 = 1.0f - h * h;
                        float d  = f1 * zd;
                        int rowv = v * 16 + pr;
                        split_hl(h, hh, hl);
                        *(_Float16*)(lds + LDS_HI + act_off(rowv, col * 2)) = hh;
                        *(_Float16*)(lds + LDS_LO + act_off(rowv, col * 2)) = hl;
                        split_hl(d, hh, hl);
                        *(_Float16*)(lds + LDS_HI + act_off(32 + rowv, col * 2)) = hh;
                        *(_Float16*)(lds + LDS_LO + act_off(32 + rowv, col * 2)) = hl;
                    }
                } else {
                    #pragma unroll
                    for (int rt = 0; rt < 4; ++rt) {
                        float z0 = am[rt][ct][r] + al[rt][ct][r] * LO_INV + bias;
                        float h  = fast_tanh(z0);
                        int row = rt * 16 + pr;
                        split_hl(h, hh, hl);
                        *(_Float16*)(lds + LDS_HI + act_off(row, col * 2)) = hh;
                        *(_Float16*)(lds + LDS_LO + act_off(row, col * 2)) = hl;
                    }
                }
            }
        }
        asm volatile("s_waitcnt lgkmcnt(0)" ::: "memory");
        __builtin_amdgcn_sched_barrier(0);
        __builtin_amdgcn_s_barrier();
        __builtin_amdgcn_sched_barrier(0);
    }

    // ---------------- layer 4: 256 -> 1 ----------------
    {
        const int row = tid >> 3;      // 64 rows
        const int seg = tid & 7;       // 8 lanes per row
        const int k0  = seg * 32;
        float d = 0.0f;
        #pragma unroll
        for (int kb = 0; kb < 32; kb += 8) {
            int kbyte = (k0 + kb) * 2;
            f16x8 h8 = *(const f16x8*)(lds + LDS_HI + act_off(row, kbyte));
            f16x8 l8 = *(const f16x8*)(lds + LDS_LO + act_off(row, kbyte));
            alignas(16) float wv[8];
            *(f32x4*)&wv[0] = *(const f32x4*)(W4 + k0 + kb);
            *(f32x4*)&wv[4] = *(const f32x4*)(W4 + k0 + kb + 4);
            #pragma unroll
            for (int j = 0; j < 8; ++j)
                d = fmaf((float)h8[j] + (float)l8[j] * LO_INV, wv[j], d);
        }
        d += __shfl_down(d, 4, 8);
        d += __shfl_down(d, 2, 8);
        d += __shfl_down(d, 1, 8);
        if (seg == 0) {
            if (S == 4) {
                if (row >= 3 * PTS) out[0 * N_PTS + pbase + (row - 3 * PTS)] = d;      // u_tt - u_xx
            } else if (S == 2) {
                if (row < PTS) out[1 * N_PTS + pbase + row] = d + b4[0];               // u_phi
                else           out[2 * N_PTS + pbase + (row - PTS)] = d;               // du/dt
            } else {
                out[3 * N_PTS + pbase + row] = d + b4[0];                              // u_bound
            }
        }
    }
}

extern "C" void kernel_launch(void* const* d_in, const int* in_sizes, int n_in,
                              void* d_out, int out_size, void* d_ws, size_t ws_size,
                              hipStream_t stream) {
    const float* W0 = (const float*)d_in[0];
    const float* b0 = (const float*)d_in[1];
    const float* W1 = (const float*)d_in[2];
    const float* b1 = (const float*)d_in[3];
    const float* W2 = (const float*)d_in[4];
    const float* b2 = (const float*)d_in[5];
    const float* W3 = (const float*)d_in[6];
    const float* b3 = (const float*)d_in[7];
    const float* W4 = (const float*)d_in[8];
    const float* b4 = (const float*)d_in[9];
    const float* tx_eq    = (const float*)d_in[10];
    const float* tx_init  = (const float*)d_in[11];
    const float* tx_bound = (const float*)d_in[12];
    float* out = (float*)d_out;
    char* wpre = (char*)d_ws;     // needs 768KB

    hipFuncSetAttribute((const void*)pinn_mfma<4,16>, hipFuncAttributeMaxDynamicSharedMemorySize, LDS_SZ);
    hipFuncSetAttribute((const void*)pinn_mfma<2,32>, hipFuncAttributeMaxDynamicSharedMemorySize, LDS_SZ);
    hipFuncSetAttribute((const void*)pinn_mfma<1,64>, hipFuncAttributeMaxDynamicSharedMemorySize, LDS_SZ);

    prep_w<<<768, 256, 0, stream>>>(W1, W2, W3, wpre);
    pinn_mfma<4,16><<<N_PTS/16, 512, LDS_SZ, stream>>>(W0,b0,b1,b2,b3,W4,b4,wpre,tx_eq,   out);
    pinn_mfma<2,32><<<N_PTS/32, 512, LDS_SZ, stream>>>(W0,b0,b1,b2,b3,W4,b4,wpre,tx_init, out);
    pinn_mfma<1,64><<<N_PTS/64, 512, LDS_SZ, stream>>>(W0,b0,b1,b2,b3,W4,b4,wpre,tx_bound,out);
}

// Round 4
// 893.416 us; speedup vs baseline: 6.2161x; 1.5626x over previous
//
#include <hip/hip_runtime.h>
#include <math.h>

#define N_PTS 131072
#define HID   256

typedef __attribute__((ext_vector_type(8))) _Float16 f16x8;
typedef __attribute__((ext_vector_type(4))) float    f32x4;
typedef unsigned int u32;
typedef __attribute__((address_space(1))) const u32 gu32;
typedef __attribute__((address_space(3))) u32       lu32;

// LDS map (dynamic, 128 KiB): act_hi[128][256] f16 (64KB) | W double-buffer (2x32KB)
#define LDS_HI  0
#define LDS_W   65536
#define LDS_SZ  131072
#define LO_SCALE 4096.0f
#define LO_INV   (1.0f/4096.0f)

// act plane: [row][k] f16, XOR swizzle -> b128 A-frag reads conflict-optimal
__device__ __forceinline__ int act_off(int row, int kbyte) {
    return row * 512 + (kbyte ^ ((row & 7) << 4));
}
// W slab in LDS: [n][32k] f16 (transposed), slot XOR on (n>>1)
__device__ __forceinline__ int w_off(int n, int kg) {
    return n * 64 + ((kg ^ ((n >> 1) & 3)) << 4);
}
__device__ __forceinline__ float fast_tanh(float z) {
    float zc = fminf(fmaxf(z, -15.0f), 15.0f);
    float t  = __expf(2.0f * zc);
    return __fdividef(t - 1.0f, t + 1.0f);
}
__device__ __forceinline__ void split_hl(float v, _Float16 &hi, _Float16 &lo) {
    hi = (_Float16)v;
    lo = (_Float16)((v - (float)hi) * LO_SCALE);
}

// Pre-split W1..W3 into f16 hi/lo, transposed to [n][k], LDS swizzle pre-applied.
// d_ws: [layer 0..2][slab 0..7] x 32KB = [hi 16KB][lo 16KB]. 768KB total.
__global__ void prep_w(const float* __restrict__ W1, const float* __restrict__ W2,
                       const float* __restrict__ W3, char* __restrict__ ws)
{
    int idx = blockIdx.x * 256 + threadIdx.x;
    int l = idx >> 16;
    int e = idx & 65535;
    int k = e >> 8, n = e & 255;
    const float* W = (l == 0) ? W1 : (l == 1) ? W2 : W3;
    float w = W[e];
    _Float16 hi, lo;
    split_hl(w, hi, lo);
    int kk = k & 31;
    int byte_in = w_off(n, kk >> 3) + (kk & 7) * 2;
    char* base = ws + (size_t)(l * 8 + (k >> 5)) * 32768;
    *(_Float16*)(base + byte_in)         = hi;
    *(_Float16*)(base + 16384 + byte_in) = lo;
}

// Fused PINN forward + Taylor streams. A = f16-hi only; W = f16 hi/lo split.
// ROWS = S*PTS = 128 GEMM rows/block; 8 waves; wave w owns cols [32w, 32w+32).
template<int S, int PTS>
__global__ void __launch_bounds__(512, 1)
pinn_mfma(const float* __restrict__ W0, const float* __restrict__ b0,
          const float* __restrict__ b1, const float* __restrict__ b2,
          const float* __restrict__ b3,
          const float* __restrict__ W4, const float* __restrict__ b4,
          const char* __restrict__ wpre,
          const float* __restrict__ tx, float* __restrict__ out)
{
    extern __shared__ char lds[];
    const int tid  = threadIdx.x;
    const int lane = tid & 63;
    const int wid  = tid >> 6;
    const int pbase = blockIdx.x * PTS;
    constexpr int CG = 512 / PTS;     // threads per point (layer 0)
    constexpr int NC = 256 / CG;      // cols per thread (layer 0)
    const int ep  = tid / CG;
    const int ec0 = (tid % CG) * NC;
    const int wcb = wid * 32;

    // ---------------- layer 0: 2 -> 256 (elementwise into LDS act-hi) ----------------
    {
        const float tt = tx[2 * (pbase + ep) + 0];
        const float xx = tx[2 * (pbase + ep) + 1];
        for (int cb = ec0; cb < ec0 + NC; cb += 8) {
            alignas(16) float w0r[8], w1r[8], bb[8];
            *(f32x4*)&w0r[0] = *(const f32x4*)(W0 + cb);
            *(f32x4*)&w0r[4] = *(const f32x4*)(W0 + cb + 4);
            *(f32x4*)&w1r[0] = *(const f32x4*)(W0 + HID + cb);
            *(f32x4*)&w1r[4] = *(const f32x4*)(W0 + HID + cb + 4);
            *(f32x4*)&bb[0]  = *(const f32x4*)(b0 + cb);
            *(f32x4*)&bb[4]  = *(const f32x4*)(b0 + cb + 4);
            f16x8 vhi[S];
            #pragma unroll
            for (int j = 0; j < 8; ++j) {
                float z = fmaf(tt, w0r[j], fmaf(xx, w1r[j], bb[j]));
                float h = fast_tanh(z);
                float f1 = 1.0f - h * h;
                vhi[0][j] = (_Float16)h;
                if (S == 2) {
                    vhi[1][j] = (_Float16)(f1 * w0r[j]);
                } else if (S == 4) {
                    float d1 = w0r[j] + w1r[j];
                    float d2 = w0r[j] - w1r[j];
                    float f2 = -2.0f * h * f1;
                    vhi[1][j] = (_Float16)(f1 * d1);
                    vhi[2][j] = (_Float16)(f1 * d2);
                    vhi[3][j] = (_Float16)(f2 * d1 * d2);
                }
            }
            #pragma unroll
            for (int s2 = 0; s2 < S; ++s2) {
                int row = s2 * PTS + ep;
                *(f16x8*)(lds + LDS_HI + act_off(row, cb * 2)) = vhi[s2];
            }
        }
    }

    // bias preload (2 cols per lane per layer)
    const int cA = wcb + (lane & 15);
    float bc[3][2];
    bc[0][0] = b1[cA]; bc[0][1] = b1[cA + 16];
    bc[1][0] = b2[cA]; bc[1][1] = b2[cA + 16];
    bc[2][0] = b3[cA]; bc[2][1] = b3[cA + 16];

    // stage slab 0 into buf0
    {
        const char* src = wpre;
        char* dst = lds + LDS_W;
        #pragma unroll
        for (int q = 0; q < 4; ++q) {
            int o = (wid * 4 + q) * 1024;
            __builtin_amdgcn_global_load_lds((gu32*)(src + o + lane * 16),
                                             (lu32*)(dst + o), 16, 0, 0);
        }
    }
    __syncthreads();

    // ---------------- layers 1..3: 256 -> 256 (A-hi x W-hi/lo MFMA) ----------------
    #pragma unroll
    for (int l = 0; l < 3; ++l) {
        f32x4 am[8][2], al[8][2];
        #pragma unroll
        for (int rt = 0; rt < 8; ++rt)
            #pragma unroll
            for (int ct = 0; ct < 2; ++ct) {
                am[rt][ct] = (f32x4){0.f, 0.f, 0.f, 0.f};
                al[rt][ct] = (f32x4){0.f, 0.f, 0.f, 0.f};
            }

        for (int s = 0; s < 8; ++s) {
            const int g = l * 8 + s;
            if (g < 23) {   // prefetch next slab into other buffer
                const char* src = wpre + (size_t)(g + 1) * 32768;
                char* dst = lds + LDS_W + ((g + 1) & 1) * 32768;
                #pragma unroll
                for (int q = 0; q < 4; ++q) {
                    int o = (wid * 4 + q) * 1024;
                    __builtin_amdgcn_global_load_lds((gu32*)(src + o + lane * 16),
                                                     (lu32*)(dst + o), 16, 0, 0);
                }
            }
            const int kbyte = s * 64 + ((lane >> 4) << 4);
            const char* wb = lds + LDS_W + (g & 1) * 32768;
            f16x8 bhi[2], blo[2];
            #pragma unroll
            for (int ct = 0; ct < 2; ++ct) {
                const int n  = wcb + ct * 16 + (lane & 15);
                const int wo = w_off(n, lane >> 4);
                bhi[ct] = *(const f16x8*)(wb + wo);
                blo[ct] = *(const f16x8*)(wb + 16384 + wo);
            }
            __builtin_amdgcn_s_setprio(1);
            #pragma unroll
            for (int rt = 0; rt < 8; ++rt) {
                const int row = rt * 16 + (lane & 15);
                f16x8 ahi = *(const f16x8*)(lds + LDS_HI + act_off(row, kbyte));
                am[rt][0] = __builtin_amdgcn_mfma_f32_16x16x32_f16(ahi, bhi[0], am[rt][0], 0, 0, 0);
                am[rt][1] = __builtin_amdgcn_mfma_f32_16x16x32_f16(ahi, bhi[1], am[rt][1], 0, 0, 0);
                al[rt][0] = __builtin_amdgcn_mfma_f32_16x16x32_f16(ahi, blo[0], al[rt][0], 0, 0, 0);
                al[rt][1] = __builtin_amdgcn_mfma_f32_16x16x32_f16(ahi, blo[1], al[rt][1], 0, 0, 0);
            }
            __builtin_amdgcn_s_setprio(0);
            __syncthreads();   // prefetch drain covered by this slab's MFMAs
        }

        // ---- in-register epilogue ----
        // C/D: row = rt*16 + (lane>>4)*4 + r, col = wcb + ct*16 + (lane&15)
        #pragma unroll
        for (int ct = 0; ct < 2; ++ct) {
            const int col = wcb + ct * 16 + (lane & 15);
            const float bias = bc[l][ct];
            #pragma unroll
            for (int r = 0; r < 4; ++r) {
                const int pr = (lane >> 4) * 4 + r;
                if (S == 4) {
                    // stream s2, point p = pp*16+pr lives in tile rt = s2*2+pp
                    #pragma unroll
                    for (int pp = 0; pp < 2; ++pp) {
                        float z0 = am[0 + pp][ct][r] + al[0 + pp][ct][r] * LO_INV + bias;
                        float z1 = am[2 + pp][ct][r] + al[2 + pp][ct][r] * LO_INV;
                        float z2 = am[4 + pp][ct][r] + al[4 + pp][ct][r] * LO_INV;
                        float zm = am[6 + pp][ct][r] + al[6 + pp][ct][r] * LO_INV;
                        float h  = fast_tanh(z0);
                        float f1 = 1.0f - h * h;
                        float f2 = -2.0f * h * f1;
                        int prow = pp * 16 + pr;
                        *(_Float16*)(lds + LDS_HI + act_off(prow,      col * 2)) = (_Float16)h;
                        *(_Float16*)(lds + LDS_HI + act_off(32 + prow, col * 2)) = (_Float16)(f1 * z1);
                        *(_Float16*)(lds + LDS_HI + act_off(64 + prow, col * 2)) = (_Float16)(f1 * z2);
                        *(_Float16*)(lds + LDS_HI + act_off(96 + prow, col * 2)) =
                            (_Float16)(fmaf(f1, zm, f2 * z1 * z2));
                    }
                } else if (S == 2) {
                    // value tiles rt=0..3 (rows 0-63), deriv tiles rt+4 (rows 64-127)
                    #pragma unroll
                    for (int rtv = 0; rtv < 4; ++rtv) {
                        float z0 = am[rtv][ct][r]     + al[rtv][ct][r]     * LO_INV + bias;
                        float zd = am[rtv + 4][ct][r] + al[rtv + 4][ct][r] * LO_INV;
                        float h  = fast_tanh(z0);
                        float f1 = 1.0f - h * h;
                        int prow = rtv * 16 + pr;
                        *(_Float16*)(lds + LDS_HI + act_off(prow,      col * 2)) = (_Float16)h;
                        *(_Float16*)(lds + LDS_HI + act_off(64 + prow, col * 2)) = (_Float16)(f1 * zd);
                    }
                } else {
                    #pragma unroll
                    for (int rt = 0; rt < 8; ++rt) {
                        float z0 = am[rt][ct][r] + al[rt][ct][r] * LO_INV + bias;
                        float h  = fast_tanh(z0);
                        *(_Float16*)(lds + LDS_HI + act_off(rt * 16 + pr, col * 2)) = (_Float16)h;
                    }
                }
            }
        }
        __syncthreads();
    }

    // ---------------- layer 4: 256 -> 1 ----------------
    if (S == 4) {
        // only the mixed stream (rows 96..127) is needed
        const int p   = tid >> 4;     // 0..31
        const int seg = tid & 15;     // 16 lanes per row
        const int k0  = seg * 16;
        const int row = 96 + p;
        float d = 0.0f;
        #pragma unroll
        for (int kb = 0; kb < 16; kb += 8) {
            f16x8 h8 = *(const f16x8*)(lds + LDS_HI + act_off(row, (k0 + kb) * 2));
            alignas(16) float wv[8];
            *(f32x4*)&wv[0] = *(const f32x4*)(W4 + k0 + kb);
            *(f32x4*)&wv[4] = *(const f32x4*)(W4 + k0 + kb + 4);
            #pragma unroll
            for (int j = 0; j < 8; ++j) d = fmaf((float)h8[j], wv[j], d);
        }
        #pragma unroll
        for (int off = 8; off > 0; off >>= 1) d += __shfl_down(d, off, 16);
        if (seg == 0) out[0 * N_PTS + pbase + p] = d;              // u_tt - u_xx
    } else {
        const int row = tid >> 2;     // 0..127
        const int seg = tid & 3;      // 4 lanes per row
        const int k0  = seg * 64;
        float d = 0.0f;
        #pragma unroll
        for (int kb = 0; kb < 64; kb += 8) {
            f16x8 h8 = *(const f16x8*)(lds + LDS_HI + act_off(row, (k0 + kb) * 2));
            alignas(16) float wv[8];
            *(f32x4*)&wv[0] = *(const f32x4*)(W4 + k0 + kb);
            *(f32x4*)&wv[4] = *(const f32x4*)(W4 + k0 + kb + 4);
            #pragma unroll
            for (int j = 0; j < 8; ++j) d = fmaf((float)h8[j], wv[j], d);
        }
        d += __shfl_down(d, 2, 4);
        d += __shfl_down(d, 1, 4);
        if (seg == 0) {
            if (S == 2) {
                if (row < 64) out[1 * N_PTS + pbase + row] = d + b4[0];        // u_phi
                else          out[2 * N_PTS + pbase + (row - 64)] = d;         // du/dt
            } else {
                out[3 * N_PTS + pbase + row] = d + b4[0];                      // u_bound
            }
        }
    }
}

extern "C" void kernel_launch(void* const* d_in, const int* in_sizes, int n_in,
                              void* d_out, int out_size, void* d_ws, size_t ws_size,
                              hipStream_t stream) {
    const float* W0 = (const float*)d_in[0];
    const float* b0 = (const float*)d_in[1];
    const float* W1 = (const float*)d_in[2];
    const float* b1 = (const float*)d_in[3];
    const float* W2 = (const float*)d_in[4];
    const float* b2 = (const float*)d_in[5];
    const float* W3 = (const float*)d_in[6];
    const float* b3 = (const float*)d_in[7];
    const float* W4 = (const float*)d_in[8];
    const float* b4 = (const float*)d_in[9];
    const float* tx_eq    = (const float*)d_in[10];
    const float* tx_init  = (const float*)d_in[11];
    const float* tx_bound = (const float*)d_in[12];
    float* out = (float*)d_out;
    char* wpre = (char*)d_ws;     // needs 768KB

    hipFuncSetAttribute((const void*)pinn_mfma<4,32>,  hipFuncAttributeMaxDynamicSharedMemorySize, LDS_SZ);
    hipFuncSetAttribute((const void*)pinn_mfma<2,64>,  hipFuncAttributeMaxDynamicSharedMemorySize, LDS_SZ);
    hipFuncSetAttribute((const void*)pinn_mfma<1,128>, hipFuncAttributeMaxDynamicSharedMemorySize, LDS_SZ);

    prep_w<<<768, 256, 0, stream>>>(W1, W2, W3, wpre);
    pinn_mfma<4,32> <<<N_PTS/32,  512, LDS_SZ, stream>>>(W0,b0,b1,b2,b3,W4,b4,wpre,tx_eq,   out);
    pinn_mfma<2,64> <<<N_PTS/64,  512, LDS_SZ, stream>>>(W0,b0,b1,b2,b3,W4,b4,wpre,tx_init, out);
    pinn_mfma<1,128><<<N_PTS/128, 512, LDS_SZ, stream>>>(W0,b0,b1,b2,b3,W4,b4,wpre,tx_bound,out);
}